// Round 3
// baseline (752.260 us; speedup 1.0000x reference)
//
#include <hip/hip_runtime.h>
#include <math.h>

#define NN 50000

typedef unsigned short u16;
typedef short bf16x8 __attribute__((ext_vector_type(8)));
typedef float floatx4 __attribute__((ext_vector_type(4)));

__device__ inline u16 f32_to_bf16(float f) {
  unsigned u = __builtin_bit_cast(unsigned, f);
  u += 0x7fffu + ((u >> 16) & 1u);   // RNE
  return (u16)(u >> 16);
}
__device__ inline float bf16_to_f32(u16 h) {
  unsigned u = ((unsigned)h) << 16;
  return __builtin_bit_cast(float, u);
}
__device__ inline float gelu_exact(float v) {
  return 0.5f * v * (1.0f + erff(v * 0.70710678118654752f));
}

// ---------------- zero cur + stats ----------------
__global__ void zero_misc_kernel(int* __restrict__ cur, float* __restrict__ stats, int n) {
  int i = blockIdx.x * blockDim.x + threadIdx.x;
  if (i < n) cur[i] = 0;
  if (i < 512) stats[i] = 0.0f;
}

// ---------------- CSR build ----------------
__global__ void hist_kernel(const int* __restrict__ dst, int* __restrict__ cnt, int E) {
  int e = blockIdx.x * blockDim.x + threadIdx.x;
  if (e < E) atomicAdd(&cnt[dst[e]], 1);
}

__global__ __launch_bounds__(256) void scan1_kernel(const int* __restrict__ cnt, int* __restrict__ ex,
                                                    int* __restrict__ btot, int n) {
  __shared__ int s[256];
  int t = threadIdx.x, i = blockIdx.x * 256 + t;
  int v = (i < n) ? cnt[i] : 0;
  s[t] = v;
  __syncthreads();
  for (int d = 1; d < 256; d <<= 1) {
    int u = (t >= d) ? s[t - d] : 0;
    __syncthreads();
    s[t] += u;
    __syncthreads();
  }
  if (i < n) ex[i] = s[t] - v;
  if (t == 255) btot[blockIdx.x] = s[255];
}

__global__ __launch_bounds__(256) void scan2_kernel(const int* __restrict__ btot, int* __restrict__ boff,
                                                    int* __restrict__ off_n, int nb) {
  __shared__ int s[256];
  int t = threadIdx.x;
  int v = (t < nb) ? btot[t] : 0;
  s[t] = v;
  __syncthreads();
  for (int d = 1; d < 256; d <<= 1) {
    int u = (t >= d) ? s[t - d] : 0;
    __syncthreads();
    s[t] += u;
    __syncthreads();
  }
  boff[t] = s[t] - v;
  if (t == 255) *off_n = s[255];
}

__global__ __launch_bounds__(256) void scan3_kernel(int* __restrict__ off, int* __restrict__ cur,
                                                    const int* __restrict__ boff, int n) {
  int i = blockIdx.x * 256 + threadIdx.x;
  if (i < n) {
    int v = off[i] + boff[blockIdx.x];
    off[i] = v;
    cur[i] = v;
  }
}

__global__ void fill_kernel(const int* __restrict__ src, const int* __restrict__ dst,
                            int* __restrict__ cur, u16* __restrict__ ssrc, int E) {
  int e = blockIdx.x * blockDim.x + threadIdx.x;
  if (e < E) {
    int p = atomicAdd(&cur[dst[e]], 1);
    ssrc[p] = (u16)src[e];
  }
}

// ---------------- weight transpose+convert: W[k][nc] fp32 -> Wt[nc][128] bf16 ----------------
__global__ void convert_w_kernel(const float* W0l, const float* W0r, const float* W1l,
                                 const float* W1r, const float* W2l, const float* W2r,
                                 u16* __restrict__ Wt) {
  int w = blockIdx.x;
  const float* src;
  int ncols;
  switch (w) {
    case 0: src = W0l; ncols = 128; break;
    case 1: src = W0r; ncols = 128; break;
    case 2: src = W1l; ncols = 128; break;
    case 3: src = W1r; ncols = 128; break;
    case 4: src = W2l; ncols = 64; break;
    default: src = W2r; ncols = 64; break;
  }
  u16* dst = Wt + w * 16384;
  int total = ncols * 128;
  for (int idx = threadIdx.x; idx < total; idx += 256) {
    int nc = idx >> 7, kk = idx & 127;           // dst[nc][kk] = W[kk][nc]
    dst[nc * 128 + kk] = f32_to_bf16(src[kk * ncols + nc]);
  }
}

// ---------------- dual bf16-MFMA GEMM with fused A-side BN+GELU ----------------
// A: [n][128] fp32. MODE 0: cast only (layer 0). MODE 1: BN(stats,g,be)+GELU then cast.
// WtL/WtR: [N][128] bf16 transposed. Cl: [n][NL] bf16. Cr: [n][NR] fp32 (+bias).
#define LOAD_CVT 0
#define LOAD_BN  1
template <int NL, int NR, int MODE>
__global__ __launch_bounds__(256) void gemm_dual_kernel(
    const float* __restrict__ A, const u16* __restrict__ WtL, const u16* __restrict__ WtR,
    const float* __restrict__ bias, const float* __restrict__ stats,
    const float* __restrict__ g, const float* __restrict__ be,
    u16* __restrict__ Cl, float* __restrict__ Cr, int n) {
  constexpr int NT = (NL + NR) / 16;
  constexpr int NTL = NL / 16;
  __shared__ u16 Wlds[NL + NR][136];   // +8 pad
  __shared__ float sc_s[128], sh_s[128];
  int t = threadIdx.x;

  if (MODE == LOAD_BN && t < 128) {
    float inv_n = 1.0f / (float)NN;
    float mu = stats[t] * inv_n;
    float var = stats[128 + t] * inv_n - mu * mu;
    float s = rsqrtf(var + 1e-5f) * g[t];
    sc_s[t] = s;
    sh_s[t] = be[t] - mu * s;
  }
  for (int idx = t; idx < (NL + NR) * 16; idx += 256) {
    int rw = idx >> 4, c8 = (idx & 15) * 8;
    const u16* srcp = (rw < NL) ? (WtL + rw * 128 + c8) : (WtR + (rw - NL) * 128 + c8);
    *(float4*)(&Wlds[rw][c8]) = *(const float4*)srcp;
  }
  __syncthreads();

  int wave = t >> 6, lane = t & 63;
  int quad = lane >> 4, l16 = lane & 15;
  int row0 = blockIdx.x * 64 + wave * 16;
  int arow = row0 + l16;
  bool rowok = arow < n;
  const float* Ap = A + (size_t)arow * 128 + quad * 8;

  floatx4 acc[NT];
#pragma unroll
  for (int i = 0; i < NT; i++) acc[i] = (floatx4){0.f, 0.f, 0.f, 0.f};

#pragma unroll
  for (int kk = 0; kk < 4; kk++) {
    bf16x8 a;
    if (rowok) {
      float4 f0 = *(const float4*)(Ap + kk * 32);
      float4 f1 = *(const float4*)(Ap + kk * 32 + 4);
      float vv[8] = {f0.x, f0.y, f0.z, f0.w, f1.x, f1.y, f1.z, f1.w};
      if (MODE == LOAD_BN) {
        int kb = quad * 8 + kk * 32;
#pragma unroll
        for (int j = 0; j < 8; j++) vv[j] = gelu_exact(vv[j] * sc_s[kb + j] + sh_s[kb + j]);
      }
#pragma unroll
      for (int j = 0; j < 8; j++) a[j] = (short)f32_to_bf16(vv[j]);
    } else {
      a = (bf16x8){0, 0, 0, 0, 0, 0, 0, 0};
    }
#pragma unroll
    for (int tile = 0; tile < NT; tile++) {
      bf16x8 b = *(const bf16x8*)(&Wlds[tile * 16 + l16][kk * 32 + quad * 8]);
      acc[tile] = __builtin_amdgcn_mfma_f32_16x16x32_bf16(a, b, acc[tile], 0, 0, 0);
    }
  }

#pragma unroll
  for (int tile = 0; tile < NT; tile++) {
#pragma unroll
    for (int r = 0; r < 4; r++) {
      int row = row0 + quad * 4 + r;
      if (row < n) {
        float v = acc[tile][r];
        if (tile < NTL) {
          int col = tile * 16 + l16;
          Cl[(size_t)row * NL + col] = f32_to_bf16(v);
        } else {
          int col = (tile - NTL) * 16 + l16;
          Cr[(size_t)row * NR + col] = v + bias[col];
        }
      }
    }
  }
}

// ---------------- aggregation (+optional fused BN stats) ----------------
// h[node][0..D) += sum_{j in CSR[node]} bf16 yl[ssrc[j]]; optionally accumulate
// per-column sum/sumsq of the FINAL h into stats[0..D) / stats[D..2D).
template <int D, bool STATS>
__global__ __launch_bounds__(256) void agg_kernel(
    const u16* __restrict__ yl, const int* __restrict__ off, const u16* __restrict__ ssrc,
    float* __restrict__ h, float* __restrict__ stats, int n) {
  constexpr int TPN = D / 8;             // threads per node, 8 cols each
  constexpr int GPB = 256 / TPN;         // node-groups per block
  int gid = threadIdx.x / TPN;
  int c8 = (threadIdx.x % TPN) * 8;
  float sum[8], sq[8];
#pragma unroll
  for (int q = 0; q < 8; q++) { sum[q] = 0.f; sq[q] = 0.f; }

  int step = gridDim.x * GPB;
  for (int node = blockIdx.x * GPB + gid; node < n; node += step) {
    int b = off[node], e = off[node + 1];
    float* hp = h + (size_t)node * D + c8;
    float4 h0 = *(const float4*)(hp);
    float4 h1 = *(const float4*)(hp + 4);
    float acc[8] = {h0.x, h0.y, h0.z, h0.w, h1.x, h1.y, h1.z, h1.w};
    int j = b;
    for (; j + 3 < e; j += 4) {
      int s0 = ssrc[j], s1 = ssrc[j + 1], s2 = ssrc[j + 2], s3 = ssrc[j + 3];
      bf16x8 v0 = *(const bf16x8*)(yl + (size_t)s0 * D + c8);
      bf16x8 v1 = *(const bf16x8*)(yl + (size_t)s1 * D + c8);
      bf16x8 v2 = *(const bf16x8*)(yl + (size_t)s2 * D + c8);
      bf16x8 v3 = *(const bf16x8*)(yl + (size_t)s3 * D + c8);
#pragma unroll
      for (int q = 0; q < 8; q++)
        acc[q] += bf16_to_f32((u16)v0[q]) + bf16_to_f32((u16)v1[q]) +
                  bf16_to_f32((u16)v2[q]) + bf16_to_f32((u16)v3[q]);
    }
    for (; j < e; j++) {
      int s0 = ssrc[j];
      bf16x8 v0 = *(const bf16x8*)(yl + (size_t)s0 * D + c8);
#pragma unroll
      for (int q = 0; q < 8; q++) acc[q] += bf16_to_f32((u16)v0[q]);
    }
    float4 o0 = {acc[0], acc[1], acc[2], acc[3]};
    float4 o1 = {acc[4], acc[5], acc[6], acc[7]};
    *(float4*)(hp) = o0;
    *(float4*)(hp + 4) = o1;
    if (STATS) {
#pragma unroll
      for (int q = 0; q < 8; q++) { sum[q] += acc[q]; sq[q] += acc[q] * acc[q]; }
    }
  }

  if (STATS) {
    __shared__ float red[GPB][D];
#pragma unroll
    for (int q = 0; q < 8; q++) red[gid][c8 + q] = sum[q];
    __syncthreads();
    for (int s = GPB / 2; s > 0; s >>= 1) {
      if (gid < s)
#pragma unroll
        for (int q = 0; q < 8; q++) red[gid][c8 + q] += red[gid + s][c8 + q];
      __syncthreads();
    }
    if (gid == 0)
#pragma unroll
      for (int q = 0; q < 8; q++) atomicAdd(&stats[c8 + q], red[0][c8 + q]);
    __syncthreads();
#pragma unroll
    for (int q = 0; q < 8; q++) red[gid][c8 + q] = sq[q];
    __syncthreads();
    for (int s = GPB / 2; s > 0; s >>= 1) {
      if (gid < s)
#pragma unroll
        for (int q = 0; q < 8; q++) red[gid][c8 + q] += red[gid + s][c8 + q];
      __syncthreads();
    }
    if (gid == 0)
#pragma unroll
      for (int q = 0; q < 8; q++) atomicAdd(&stats[D + c8 + q], red[0][c8 + q]);
  }
}

extern "C" void kernel_launch(void* const* d_in, const int* in_sizes, int n_in,
                              void* d_out, int out_size, void* d_ws, size_t ws_size,
                              hipStream_t stream) {
  const float* x   = (const float*)d_in[0];
  const int* edge  = (const int*)d_in[1];
  const int E = in_sizes[1] / 2;
  const int* esrc = edge;
  const int* edst = edge + E;
  const float* W0l = (const float*)d_in[2];
  const float* W0r = (const float*)d_in[3];
  const float* b0  = (const float*)d_in[4];
  const float* g0  = (const float*)d_in[5];
  const float* be0 = (const float*)d_in[6];
  const float* W1l = (const float*)d_in[7];
  const float* W1r = (const float*)d_in[8];
  const float* b1  = (const float*)d_in[9];
  const float* g1  = (const float*)d_in[10];
  const float* be1 = (const float*)d_in[11];
  const float* W2l = (const float*)d_in[12];
  const float* W2r = (const float*)d_in[13];
  const float* b2  = (const float*)d_in[14];
  float* out = (float*)d_out;

  const int n = NN;
  // ---- workspace layout ----
  int* off   = (int*)d_ws;               // 50304
  int* cur   = off + 50304;              // 50304
  int* btot  = cur + 50304;              // 256
  int* boff  = btot + 256;               // 256
  float* stats = (float*)(boff + 256);   // 512 (stats0 | stats1)
  u16* ssrc  = (u16*)(stats + 512);      // 800064 u16
  u16* Wt    = ssrc + 800064;            // 6*16384
  u16* ylb   = Wt + 6 * 16384;           // n*128 bf16
  float* ha  = (float*)(ylb + (size_t)n * 128);  // n*128 fp32
  float* hb  = ha + (size_t)n * 128;             // n*128 fp32
  float* stats0 = stats;
  float* stats1 = stats + 256;

  const int TB = 256;
  const int NB1 = (n + 255) / 256;

  // ---- CSR build ----
  zero_misc_kernel<<<NB1, TB, 0, stream>>>(cur, stats, n);
  hist_kernel<<<(E + TB - 1) / TB, TB, 0, stream>>>(edst, cur, E);
  scan1_kernel<<<NB1, TB, 0, stream>>>(cur, off, btot, n);
  scan2_kernel<<<1, TB, 0, stream>>>(btot, boff, off + n, NB1);
  scan3_kernel<<<NB1, TB, 0, stream>>>(off, cur, boff, n);
  fill_kernel<<<(E + TB - 1) / TB, TB, 0, stream>>>(esrc, edst, cur, ssrc, E);

  convert_w_kernel<<<6, TB, 0, stream>>>(W0l, W0r, W1l, W1r, W2l, W2r, Wt);

  const int GB = (n + 63) / 64;
  const int AB = 1024;

  // ---- layer 0: gemm(x) -> ylb, ha; agg+stats0 ----
  gemm_dual_kernel<128, 128, LOAD_CVT><<<GB, TB, 0, stream>>>(
      x, Wt + 0 * 16384, Wt + 1 * 16384, b0, nullptr, nullptr, nullptr, ylb, ha, n);
  agg_kernel<128, true><<<AB, TB, 0, stream>>>(ylb, off, ssrc, ha, stats0, n);

  // ---- layer 1: gemm(BN0+GELU(ha)) -> ylb, hb; agg+stats1 ----
  gemm_dual_kernel<128, 128, LOAD_BN><<<GB, TB, 0, stream>>>(
      ha, Wt + 2 * 16384, Wt + 3 * 16384, b1, stats0, g0, be0, ylb, hb, n);
  agg_kernel<128, true><<<AB, TB, 0, stream>>>(ylb, off, ssrc, hb, stats1, n);

  // ---- layer 2: gemm(BN1+GELU(hb)) -> ylb, out; agg ----
  gemm_dual_kernel<64, 64, LOAD_BN><<<GB, TB, 0, stream>>>(
      hb, Wt + 4 * 16384, Wt + 5 * 16384, b2, stats1, g1, be1, ylb, out, n);
  agg_kernel<64, false><<<AB, TB, 0, stream>>>(ylb, off, ssrc, out, nullptr, n);
}

// Round 4
// 427.243 us; speedup vs baseline: 1.7607x; 1.7607x over previous
//
#include <hip/hip_runtime.h>
#include <math.h>

#define NN 50000

typedef unsigned short u16;
typedef short bf16x8 __attribute__((ext_vector_type(8)));
typedef float floatx4 __attribute__((ext_vector_type(4)));

__device__ inline u16 f32_to_bf16(float f) {
  unsigned u = __builtin_bit_cast(unsigned, f);
  u += 0x7fffu + ((u >> 16) & 1u);   // RNE
  return (u16)(u >> 16);
}
__device__ inline float bf16_to_f32(u16 h) {
  unsigned u = ((unsigned)h) << 16;
  return __builtin_bit_cast(float, u);
}
__device__ inline float gelu_exact(float v) {
  return 0.5f * v * (1.0f + erff(v * 0.70710678118654752f));
}

// ---------------- zero cur + stats ----------------
__global__ void zero_misc_kernel(int* __restrict__ cur, float* __restrict__ stats, int n) {
  int i = blockIdx.x * blockDim.x + threadIdx.x;
  if (i < n) cur[i] = 0;
  if (i < 512) stats[i] = 0.0f;
}

// ---------------- CSR build ----------------
__global__ void hist_kernel(const int* __restrict__ dst, int* __restrict__ cnt, int E) {
  int e = blockIdx.x * blockDim.x + threadIdx.x;
  if (e < E) atomicAdd(&cnt[dst[e]], 1);
}

__global__ __launch_bounds__(256) void scan1_kernel(const int* __restrict__ cnt, int* __restrict__ ex,
                                                    int* __restrict__ btot, int n) {
  __shared__ int s[256];
  int t = threadIdx.x, i = blockIdx.x * 256 + t;
  int v = (i < n) ? cnt[i] : 0;
  s[t] = v;
  __syncthreads();
  for (int d = 1; d < 256; d <<= 1) {
    int u = (t >= d) ? s[t - d] : 0;
    __syncthreads();
    s[t] += u;
    __syncthreads();
  }
  if (i < n) ex[i] = s[t] - v;
  if (t == 255) btot[blockIdx.x] = s[255];
}

__global__ __launch_bounds__(256) void scan2_kernel(const int* __restrict__ btot, int* __restrict__ boff,
                                                    int* __restrict__ off_n, int nb) {
  __shared__ int s[256];
  int t = threadIdx.x;
  int v = (t < nb) ? btot[t] : 0;
  s[t] = v;
  __syncthreads();
  for (int d = 1; d < 256; d <<= 1) {
    int u = (t >= d) ? s[t - d] : 0;
    __syncthreads();
    s[t] += u;
    __syncthreads();
  }
  boff[t] = s[t] - v;
  if (t == 255) *off_n = s[255];
}

__global__ __launch_bounds__(256) void scan3_kernel(int* __restrict__ off, int* __restrict__ cur,
                                                    const int* __restrict__ boff, int n) {
  int i = blockIdx.x * 256 + threadIdx.x;
  if (i < n) {
    int v = off[i] + boff[blockIdx.x];
    off[i] = v;
    cur[i] = v;
  }
}

__global__ void fill_kernel(const int* __restrict__ src, const int* __restrict__ dst,
                            int* __restrict__ cur, u16* __restrict__ ssrc, int E) {
  int e = blockIdx.x * blockDim.x + threadIdx.x;
  if (e < E) {
    int p = atomicAdd(&cur[dst[e]], 1);
    ssrc[p] = (u16)src[e];
  }
}

// ---------------- weight transpose+convert: W[k][nc] fp32 -> Wt[nc][128] bf16 ----------------
__global__ void convert_w_kernel(const float* W0l, const float* W0r, const float* W1l,
                                 const float* W1r, const float* W2l, const float* W2r,
                                 u16* __restrict__ Wt) {
  int w = blockIdx.x;
  const float* src;
  int ncols;
  switch (w) {
    case 0: src = W0l; ncols = 128; break;
    case 1: src = W0r; ncols = 128; break;
    case 2: src = W1l; ncols = 128; break;
    case 3: src = W1r; ncols = 128; break;
    case 4: src = W2l; ncols = 64; break;
    default: src = W2r; ncols = 64; break;
  }
  u16* dst = Wt + w * 16384;
  int total = ncols * 128;
  for (int idx = threadIdx.x; idx < total; idx += 256) {
    int nc = idx >> 7, kk = idx & 127;           // dst[nc][kk] = W[kk][nc]
    dst[nc * 128 + kk] = f32_to_bf16(src[kk * ncols + nc]);
  }
}

// ---------------- dual bf16-MFMA GEMM with fused A-side BN+GELU ----------------
// A: [n][128] fp32. MODE 0: cast only (layer 0). MODE 1: BN(stats,g,be)+GELU then cast.
// WtL/WtR: [N][128] bf16 transposed. Cl: [n][NL] bf16. Cr: [n][NR] fp32 (+bias).
#define LOAD_CVT 0
#define LOAD_BN  1
template <int NL, int NR, int MODE>
__global__ __launch_bounds__(256) void gemm_dual_kernel(
    const float* __restrict__ A, const u16* __restrict__ WtL, const u16* __restrict__ WtR,
    const float* __restrict__ bias, const float* __restrict__ stats,
    const float* __restrict__ g, const float* __restrict__ be,
    u16* __restrict__ Cl, float* __restrict__ Cr, int n) {
  constexpr int NT = (NL + NR) / 16;
  constexpr int NTL = NL / 16;
  __shared__ u16 Wlds[NL + NR][136];   // +8 pad
  __shared__ float sc_s[128], sh_s[128];
  int t = threadIdx.x;

  if (MODE == LOAD_BN && t < 128) {
    float inv_n = 1.0f / (float)NN;
    float mu = stats[t] * inv_n;
    float var = stats[128 + t] * inv_n - mu * mu;
    float s = rsqrtf(var + 1e-5f) * g[t];
    sc_s[t] = s;
    sh_s[t] = be[t] - mu * s;
  }
  for (int idx = t; idx < (NL + NR) * 16; idx += 256) {
    int rw = idx >> 4, c8 = (idx & 15) * 8;
    const u16* srcp = (rw < NL) ? (WtL + rw * 128 + c8) : (WtR + (rw - NL) * 128 + c8);
    *(float4*)(&Wlds[rw][c8]) = *(const float4*)srcp;
  }
  __syncthreads();

  int wave = t >> 6, lane = t & 63;
  int quad = lane >> 4, l16 = lane & 15;
  int row0 = blockIdx.x * 64 + wave * 16;
  int arow = row0 + l16;
  bool rowok = arow < n;
  const float* Ap = A + (size_t)arow * 128 + quad * 8;

  floatx4 acc[NT];
#pragma unroll
  for (int i = 0; i < NT; i++) acc[i] = (floatx4){0.f, 0.f, 0.f, 0.f};

#pragma unroll
  for (int kk = 0; kk < 4; kk++) {
    bf16x8 a;
    if (rowok) {
      float4 f0 = *(const float4*)(Ap + kk * 32);
      float4 f1 = *(const float4*)(Ap + kk * 32 + 4);
      float vv[8] = {f0.x, f0.y, f0.z, f0.w, f1.x, f1.y, f1.z, f1.w};
      if (MODE == LOAD_BN) {
        int kb = quad * 8 + kk * 32;
#pragma unroll
        for (int j = 0; j < 8; j++) vv[j] = gelu_exact(vv[j] * sc_s[kb + j] + sh_s[kb + j]);
      }
#pragma unroll
      for (int j = 0; j < 8; j++) a[j] = (short)f32_to_bf16(vv[j]);
    } else {
      a = (bf16x8){0, 0, 0, 0, 0, 0, 0, 0};
    }
#pragma unroll
    for (int tile = 0; tile < NT; tile++) {
      bf16x8 b = *(const bf16x8*)(&Wlds[tile * 16 + l16][kk * 32 + quad * 8]);
      acc[tile] = __builtin_amdgcn_mfma_f32_16x16x32_bf16(a, b, acc[tile], 0, 0, 0);
    }
  }

#pragma unroll
  for (int tile = 0; tile < NT; tile++) {
#pragma unroll
    for (int r = 0; r < 4; r++) {
      int row = row0 + quad * 4 + r;
      if (row < n) {
        float v = acc[tile][r];
        if (tile < NTL) {
          int col = tile * 16 + l16;
          Cl[(size_t)row * NL + col] = f32_to_bf16(v);
        } else {
          int col = (tile - NTL) * 16 + l16;
          Cr[(size_t)row * NR + col] = v + bias[col];
        }
      }
    }
  }
}

// ---------------- aggregation: round-2 proven shape ----------------
// one node per (D/4)-lane group, 4 cols per lane, ushort4 gathers, big grid.
template <int D>
__global__ __launch_bounds__(256) void aggregate_kernel(
    const u16* __restrict__ yl, const int* __restrict__ off,
    const u16* __restrict__ ssrc, float* __restrict__ h, int n) {
  constexpr int TPN = D / 4;             // threads per node (4 cols each)
  constexpr int NPB = 256 / TPN;
  int node = blockIdx.x * NPB + threadIdx.x / TPN;
  int c4 = (threadIdx.x % TPN) * 4;
  if (node >= n) return;
  int b = off[node], e = off[node + 1];
  float4 acc = *(const float4*)(h + (size_t)node * D + c4);
  int j = b;
  for (; j + 3 < e; j += 4) {
    int s0 = ssrc[j], s1 = ssrc[j + 1], s2 = ssrc[j + 2], s3 = ssrc[j + 3];
    ushort4 v0 = *(const ushort4*)(yl + (size_t)s0 * D + c4);
    ushort4 v1 = *(const ushort4*)(yl + (size_t)s1 * D + c4);
    ushort4 v2 = *(const ushort4*)(yl + (size_t)s2 * D + c4);
    ushort4 v3 = *(const ushort4*)(yl + (size_t)s3 * D + c4);
    acc.x += bf16_to_f32(v0.x) + bf16_to_f32(v1.x) + bf16_to_f32(v2.x) + bf16_to_f32(v3.x);
    acc.y += bf16_to_f32(v0.y) + bf16_to_f32(v1.y) + bf16_to_f32(v2.y) + bf16_to_f32(v3.y);
    acc.z += bf16_to_f32(v0.z) + bf16_to_f32(v1.z) + bf16_to_f32(v2.z) + bf16_to_f32(v3.z);
    acc.w += bf16_to_f32(v0.w) + bf16_to_f32(v1.w) + bf16_to_f32(v2.w) + bf16_to_f32(v3.w);
  }
  for (; j < e; j++) {
    int s0 = ssrc[j];
    ushort4 v0 = *(const ushort4*)(yl + (size_t)s0 * D + c4);
    acc.x += bf16_to_f32(v0.x); acc.y += bf16_to_f32(v0.y);
    acc.z += bf16_to_f32(v0.z); acc.w += bf16_to_f32(v0.w);
  }
  *(float4*)(h + (size_t)node * D + c4) = acc;
}

// ---------------- BN stats (separate, proven) ----------------
__global__ __launch_bounds__(256) void bnstats_kernel(
    const float* __restrict__ h, float* __restrict__ stats, int n) {
  int c = threadIdx.x & 127;
  int half = threadIdx.x >> 7;
  float sum = 0.f, sq = 0.f;
  for (int r = blockIdx.x * 2 + half; r < n; r += gridDim.x * 2) {
    float v = h[(size_t)r * 128 + c];
    sum += v; sq += v * v;
  }
  __shared__ float ls[256], lq[256];
  ls[threadIdx.x] = sum; lq[threadIdx.x] = sq;
  __syncthreads();
  if (threadIdx.x < 128) {
    sum = ls[threadIdx.x] + ls[threadIdx.x + 128];
    sq = lq[threadIdx.x] + lq[threadIdx.x + 128];
    atomicAdd(&stats[c], sum);
    atomicAdd(&stats[128 + c], sq);
  }
}

extern "C" void kernel_launch(void* const* d_in, const int* in_sizes, int n_in,
                              void* d_out, int out_size, void* d_ws, size_t ws_size,
                              hipStream_t stream) {
  const float* x   = (const float*)d_in[0];
  const int* edge  = (const int*)d_in[1];
  const int E = in_sizes[1] / 2;
  const int* esrc = edge;
  const int* edst = edge + E;
  const float* W0l = (const float*)d_in[2];
  const float* W0r = (const float*)d_in[3];
  const float* b0  = (const float*)d_in[4];
  const float* g0  = (const float*)d_in[5];
  const float* be0 = (const float*)d_in[6];
  const float* W1l = (const float*)d_in[7];
  const float* W1r = (const float*)d_in[8];
  const float* b1  = (const float*)d_in[9];
  const float* g1  = (const float*)d_in[10];
  const float* be1 = (const float*)d_in[11];
  const float* W2l = (const float*)d_in[12];
  const float* W2r = (const float*)d_in[13];
  const float* b2  = (const float*)d_in[14];
  float* out = (float*)d_out;

  const int n = NN;
  // ---- workspace layout ----
  int* off   = (int*)d_ws;               // 50304
  int* cur   = off + 50304;              // 50304
  int* btot  = cur + 50304;              // 256
  int* boff  = btot + 256;               // 256
  float* stats = (float*)(boff + 256);   // 512 (stats0 | stats1)
  u16* ssrc  = (u16*)(stats + 512);      // 800064 u16
  u16* Wt    = ssrc + 800064;            // 6*16384
  u16* ylb   = Wt + 6 * 16384;           // n*128 bf16
  float* ha  = (float*)(ylb + (size_t)n * 128);  // n*128 fp32
  float* hb  = ha + (size_t)n * 128;             // n*128 fp32
  float* stats0 = stats;
  float* stats1 = stats + 256;

  const int TB = 256;
  const int NB1 = (n + 255) / 256;

  // ---- CSR build ----
  zero_misc_kernel<<<NB1, TB, 0, stream>>>(cur, stats, n);
  hist_kernel<<<(E + TB - 1) / TB, TB, 0, stream>>>(edst, cur, E);
  scan1_kernel<<<NB1, TB, 0, stream>>>(cur, off, btot, n);
  scan2_kernel<<<1, TB, 0, stream>>>(btot, boff, off + n, NB1);
  scan3_kernel<<<NB1, TB, 0, stream>>>(off, cur, boff, n);
  fill_kernel<<<(E + TB - 1) / TB, TB, 0, stream>>>(esrc, edst, cur, ssrc, E);

  convert_w_kernel<<<6, TB, 0, stream>>>(W0l, W0r, W1l, W1r, W2l, W2r, Wt);

  const int GB = (n + 63) / 64;

  // ---- layer 0: gemm(x) -> ylb, ha; agg; stats0 ----
  gemm_dual_kernel<128, 128, LOAD_CVT><<<GB, TB, 0, stream>>>(
      x, Wt + 0 * 16384, Wt + 1 * 16384, b0, nullptr, nullptr, nullptr, ylb, ha, n);
  aggregate_kernel<128><<<(n + 7) / 8, TB, 0, stream>>>(ylb, off, ssrc, ha, n);
  bnstats_kernel<<<256, TB, 0, stream>>>(ha, stats0, n);

  // ---- layer 1: gemm(BN0+GELU(ha)) -> ylb, hb; agg; stats1 ----
  gemm_dual_kernel<128, 128, LOAD_BN><<<GB, TB, 0, stream>>>(
      ha, Wt + 2 * 16384, Wt + 3 * 16384, b1, stats0, g0, be0, ylb, hb, n);
  aggregate_kernel<128><<<(n + 7) / 8, TB, 0, stream>>>(ylb, off, ssrc, hb, n);
  bnstats_kernel<<<256, TB, 0, stream>>>(hb, stats1, n);

  // ---- layer 2: gemm(BN1+GELU(hb)) -> ylb, out; agg ----
  gemm_dual_kernel<64, 64, LOAD_BN><<<GB, TB, 0, stream>>>(
      hb, Wt + 4 * 16384, Wt + 5 * 16384, b2, stats1, g1, be1, ylb, out, n);
  aggregate_kernel<64><<<(n + 15) / 16, TB, 0, stream>>>(ylb, off, ssrc, out, n);
}

// Round 5
// 426.595 us; speedup vs baseline: 1.7634x; 1.0015x over previous
//
#include <hip/hip_runtime.h>
#include <math.h>

#define NN 50000

typedef unsigned short u16;
typedef short bf16x8 __attribute__((ext_vector_type(8)));
typedef float floatx4 __attribute__((ext_vector_type(4)));

__device__ inline u16 f32_to_bf16(float f) {
  unsigned u = __builtin_bit_cast(unsigned, f);
  u += 0x7fffu + ((u >> 16) & 1u);   // RNE
  return (u16)(u >> 16);
}
__device__ inline float bf16_to_f32(u16 h) {
  unsigned u = ((unsigned)h) << 16;
  return __builtin_bit_cast(float, u);
}
__device__ inline float gelu_exact(float v) {
  return 0.5f * v * (1.0f + erff(v * 0.70710678118654752f));
}

// ---------------- zero cur + stats ----------------
__global__ void zero_misc_kernel(int* __restrict__ cur, float* __restrict__ stats, int n) {
  int i = blockIdx.x * blockDim.x + threadIdx.x;
  if (i < n) cur[i] = 0;
  if (i < 512) stats[i] = 0.0f;
}

// ---------------- CSR build ----------------
__global__ void hist_kernel(const int* __restrict__ dst, int* __restrict__ cnt, int E) {
  int e = blockIdx.x * blockDim.x + threadIdx.x;
  if (e < E) atomicAdd(&cnt[dst[e]], 1);
}

__global__ __launch_bounds__(256) void scan1_kernel(const int* __restrict__ cnt, int* __restrict__ ex,
                                                    int* __restrict__ btot, int n) {
  __shared__ int s[256];
  int t = threadIdx.x, i = blockIdx.x * 256 + t;
  int v = (i < n) ? cnt[i] : 0;
  s[t] = v;
  __syncthreads();
  for (int d = 1; d < 256; d <<= 1) {
    int u = (t >= d) ? s[t - d] : 0;
    __syncthreads();
    s[t] += u;
    __syncthreads();
  }
  if (i < n) ex[i] = s[t] - v;
  if (t == 255) btot[blockIdx.x] = s[255];
}

__global__ __launch_bounds__(256) void scan2_kernel(const int* __restrict__ btot, int* __restrict__ boff,
                                                    int* __restrict__ off_n, int nb) {
  __shared__ int s[256];
  int t = threadIdx.x;
  int v = (t < nb) ? btot[t] : 0;
  s[t] = v;
  __syncthreads();
  for (int d = 1; d < 256; d <<= 1) {
    int u = (t >= d) ? s[t - d] : 0;
    __syncthreads();
    s[t] += u;
    __syncthreads();
  }
  boff[t] = s[t] - v;
  if (t == 255) *off_n = s[255];
}

__global__ __launch_bounds__(256) void scan3_kernel(int* __restrict__ off, int* __restrict__ cur,
                                                    const int* __restrict__ boff, int n) {
  int i = blockIdx.x * 256 + threadIdx.x;
  if (i < n) {
    int v = off[i] + boff[blockIdx.x];
    off[i] = v;
    cur[i] = v;
  }
}

__global__ void fill_kernel(const int* __restrict__ src, const int* __restrict__ dst,
                            int* __restrict__ cur, u16* __restrict__ ssrc, int E) {
  int e = blockIdx.x * blockDim.x + threadIdx.x;
  if (e < E) {
    int p = atomicAdd(&cur[dst[e]], 1);
    ssrc[p] = (u16)src[e];
  }
}

// ---------------- weight transpose+convert: W[k][nc] fp32 -> Wt[nc][128] bf16 ----------------
__global__ void convert_w_kernel(const float* W0l, const float* W0r, const float* W1l,
                                 const float* W1r, const float* W2l, const float* W2r,
                                 u16* __restrict__ Wt) {
  int w = blockIdx.x;
  const float* src;
  int ncols;
  switch (w) {
    case 0: src = W0l; ncols = 128; break;
    case 1: src = W0r; ncols = 128; break;
    case 2: src = W1l; ncols = 128; break;
    case 3: src = W1r; ncols = 128; break;
    case 4: src = W2l; ncols = 64; break;
    default: src = W2r; ncols = 64; break;
  }
  u16* dst = Wt + w * 16384;
  int total = ncols * 128;
  for (int idx = threadIdx.x; idx < total; idx += 256) {
    int nc = idx >> 7, kk = idx & 127;           // dst[nc][kk] = W[kk][nc]
    dst[nc * 128 + kk] = f32_to_bf16(src[kk * ncols + nc]);
  }
}

// ---------------- dual bf16-MFMA GEMM with fused A-side BN+GELU ----------------
// A: [n][128] fp32. MODE 0: cast only (layer 0). MODE 1: BN+GELU then cast.
// WtL/WtR: [N][128] bf16 transposed. Cl: [n][NL] bf16. Cr: [n][NR] fp32 (+bias).
// W staged in LDS with XOR-16B-chunk swizzle (phys chunk = chunk ^ (row&15)):
// row stride 256B == 0 mod banks, so the XOR spreads each quad's 16 lanes over
// all 16 chunks -> 2-way bank aliasing (free, m136). No padding, exact 2^k size.
// Each wave computes TWO 16-row M-tiles (32 rows) so every B-fragment ds_read
// feeds 2 MFMAs; block = 4 waves = 128 rows, W staged once per 128 rows.
#define LOAD_CVT 0
#define LOAD_BN  1
template <int NL, int NR, int MODE>
__global__ __launch_bounds__(256, 2) void gemm_dual_kernel(
    const float* __restrict__ A, const u16* __restrict__ WtL, const u16* __restrict__ WtR,
    const float* __restrict__ bias, const float* __restrict__ stats,
    const float* __restrict__ g, const float* __restrict__ be,
    u16* __restrict__ Cl, float* __restrict__ Cr, int n) {
  constexpr int NTOT = NL + NR;
  constexpr int NT = NTOT / 16;
  constexpr int NTL = NL / 16;
  __shared__ u16 Wlds[NTOT * 128];
  __shared__ float sc_s[128], sh_s[128];
  int t = threadIdx.x;

  if (MODE == LOAD_BN && t < 128) {
    float inv_n = 1.0f / (float)NN;
    float mu = stats[t] * inv_n;
    float var = stats[128 + t] * inv_n - mu * mu;
    float s = rsqrtf(var + 1e-5f) * g[t];
    sc_s[t] = s;
    sh_s[t] = be[t] - mu * s;
  }
  // stage W swizzled, 16B chunks
  for (int idx = t; idx < NTOT * 16; idx += 256) {
    int rw = idx >> 4, c = idx & 15;
    const u16* srcp = (rw < NL) ? (WtL + rw * 128 + c * 8) : (WtR + (rw - NL) * 128 + c * 8);
    *(float4*)(&Wlds[rw * 128 + ((c ^ (rw & 15)) * 8)]) = *(const float4*)srcp;
  }
  __syncthreads();

  int wave = t >> 6, lane = t & 63;
  int quad = lane >> 4, l16 = lane & 15;
  int row0 = blockIdx.x * 128 + wave * 32;        // wave owns rows row0..row0+31
  int ar0 = row0 + l16, ar1 = row0 + 16 + l16;
  bool ok0 = ar0 < n, ok1 = ar1 < n;
  const float* Ap0 = A + (size_t)ar0 * 128 + quad * 8;
  const float* Ap1 = A + (size_t)ar1 * 128 + quad * 8;

  floatx4 acc0[NT], acc1[NT];
#pragma unroll
  for (int i = 0; i < NT; i++) {
    acc0[i] = (floatx4){0.f, 0.f, 0.f, 0.f};
    acc1[i] = (floatx4){0.f, 0.f, 0.f, 0.f};
  }

#pragma unroll
  for (int kk = 0; kk < 4; kk++) {
    bf16x8 a0, a1;
    {
      float vv[16];
      if (ok0) {
        float4 f0 = *(const float4*)(Ap0 + kk * 32);
        float4 f1 = *(const float4*)(Ap0 + kk * 32 + 4);
        vv[0] = f0.x; vv[1] = f0.y; vv[2] = f0.z; vv[3] = f0.w;
        vv[4] = f1.x; vv[5] = f1.y; vv[6] = f1.z; vv[7] = f1.w;
      } else {
#pragma unroll
        for (int j = 0; j < 8; j++) vv[j] = 0.f;
      }
      if (ok1) {
        float4 f0 = *(const float4*)(Ap1 + kk * 32);
        float4 f1 = *(const float4*)(Ap1 + kk * 32 + 4);
        vv[8] = f0.x; vv[9] = f0.y; vv[10] = f0.z; vv[11] = f0.w;
        vv[12] = f1.x; vv[13] = f1.y; vv[14] = f1.z; vv[15] = f1.w;
      } else {
#pragma unroll
        for (int j = 8; j < 16; j++) vv[j] = 0.f;
      }
      if (MODE == LOAD_BN) {
        int kb = kk * 32 + quad * 8;
#pragma unroll
        for (int j = 0; j < 8; j++) {
          float sc = sc_s[kb + j], sh = sh_s[kb + j];
          if (ok0) vv[j] = gelu_exact(vv[j] * sc + sh);
          if (ok1) vv[8 + j] = gelu_exact(vv[8 + j] * sc + sh);
        }
      }
#pragma unroll
      for (int j = 0; j < 8; j++) {
        a0[j] = (short)f32_to_bf16(vv[j]);
        a1[j] = (short)f32_to_bf16(vv[8 + j]);
      }
    }
    int chunk8 = ((kk * 4 + quad) ^ l16) * 8;   // swizzled 16B chunk offset (u16 units)
    const u16* wp = &Wlds[l16 * 128 + chunk8];
#pragma unroll
    for (int tile = 0; tile < NT; tile++) {
      bf16x8 b = *(const bf16x8*)(wp + tile * 2048);   // tile*16 rows * 128 u16
      acc0[tile] = __builtin_amdgcn_mfma_f32_16x16x32_bf16(a0, b, acc0[tile], 0, 0, 0);
      acc1[tile] = __builtin_amdgcn_mfma_f32_16x16x32_bf16(a1, b, acc1[tile], 0, 0, 0);
    }
  }

#pragma unroll
  for (int tile = 0; tile < NT; tile++) {
#pragma unroll
    for (int r = 0; r < 4; r++) {
      int rowA = row0 + quad * 4 + r;
      int rowB = rowA + 16;
      if (tile < NTL) {
        int col = tile * 16 + l16;
        if (rowA < n) Cl[(size_t)rowA * NL + col] = f32_to_bf16(acc0[tile][r]);
        if (rowB < n) Cl[(size_t)rowB * NL + col] = f32_to_bf16(acc1[tile][r]);
      } else {
        int col = (tile - NTL) * 16 + l16;
        float bv = bias[col];
        if (rowA < n) Cr[(size_t)rowA * NR + col] = acc0[tile][r] + bv;
        if (rowB < n) Cr[(size_t)rowB * NR + col] = acc1[tile][r] + bv;
      }
    }
  }
}

// ---------------- aggregation: one node per (D/4)-lane group, unroll 8 ----------------
template <int D>
__global__ __launch_bounds__(256) void aggregate_kernel(
    const u16* __restrict__ yl, const int* __restrict__ off,
    const u16* __restrict__ ssrc, float* __restrict__ h, int n) {
  constexpr int TPN = D / 4;             // threads per node (4 cols each)
  constexpr int NPB = 256 / TPN;
  int node = blockIdx.x * NPB + threadIdx.x / TPN;
  int c4 = (threadIdx.x % TPN) * 4;
  if (node >= n) return;
  int b = off[node], e = off[node + 1];
  float4 acc = *(const float4*)(h + (size_t)node * D + c4);
  int j = b;
  for (; j + 7 < e; j += 8) {
    int s0 = ssrc[j], s1 = ssrc[j + 1], s2 = ssrc[j + 2], s3 = ssrc[j + 3];
    int s4 = ssrc[j + 4], s5 = ssrc[j + 5], s6 = ssrc[j + 6], s7 = ssrc[j + 7];
    ushort4 v0 = *(const ushort4*)(yl + (size_t)s0 * D + c4);
    ushort4 v1 = *(const ushort4*)(yl + (size_t)s1 * D + c4);
    ushort4 v2 = *(const ushort4*)(yl + (size_t)s2 * D + c4);
    ushort4 v3 = *(const ushort4*)(yl + (size_t)s3 * D + c4);
    ushort4 v4 = *(const ushort4*)(yl + (size_t)s4 * D + c4);
    ushort4 v5 = *(const ushort4*)(yl + (size_t)s5 * D + c4);
    ushort4 v6 = *(const ushort4*)(yl + (size_t)s6 * D + c4);
    ushort4 v7 = *(const ushort4*)(yl + (size_t)s7 * D + c4);
    acc.x += bf16_to_f32(v0.x) + bf16_to_f32(v1.x) + bf16_to_f32(v2.x) + bf16_to_f32(v3.x)
           + bf16_to_f32(v4.x) + bf16_to_f32(v5.x) + bf16_to_f32(v6.x) + bf16_to_f32(v7.x);
    acc.y += bf16_to_f32(v0.y) + bf16_to_f32(v1.y) + bf16_to_f32(v2.y) + bf16_to_f32(v3.y)
           + bf16_to_f32(v4.y) + bf16_to_f32(v5.y) + bf16_to_f32(v6.y) + bf16_to_f32(v7.y);
    acc.z += bf16_to_f32(v0.z) + bf16_to_f32(v1.z) + bf16_to_f32(v2.z) + bf16_to_f32(v3.z)
           + bf16_to_f32(v4.z) + bf16_to_f32(v5.z) + bf16_to_f32(v6.z) + bf16_to_f32(v7.z);
    acc.w += bf16_to_f32(v0.w) + bf16_to_f32(v1.w) + bf16_to_f32(v2.w) + bf16_to_f32(v3.w)
           + bf16_to_f32(v4.w) + bf16_to_f32(v5.w) + bf16_to_f32(v6.w) + bf16_to_f32(v7.w);
  }
  for (; j < e; j++) {
    int s0 = ssrc[j];
    ushort4 v0 = *(const ushort4*)(yl + (size_t)s0 * D + c4);
    acc.x += bf16_to_f32(v0.x); acc.y += bf16_to_f32(v0.y);
    acc.z += bf16_to_f32(v0.z); acc.w += bf16_to_f32(v0.w);
  }
  *(float4*)(h + (size_t)node * D + c4) = acc;
}

// ---------------- BN stats ----------------
__global__ __launch_bounds__(256) void bnstats_kernel(
    const float* __restrict__ h, float* __restrict__ stats, int n) {
  int c = threadIdx.x & 127;
  int half = threadIdx.x >> 7;
  float sum = 0.f, sq = 0.f;
  for (int r = blockIdx.x * 2 + half; r < n; r += gridDim.x * 2) {
    float v = h[(size_t)r * 128 + c];
    sum += v; sq += v * v;
  }
  __shared__ float ls[256], lq[256];
  ls[threadIdx.x] = sum; lq[threadIdx.x] = sq;
  __syncthreads();
  if (threadIdx.x < 128) {
    sum = ls[threadIdx.x] + ls[threadIdx.x + 128];
    sq = lq[threadIdx.x] + lq[threadIdx.x + 128];
    atomicAdd(&stats[c], sum);
    atomicAdd(&stats[128 + c], sq);
  }
}

extern "C" void kernel_launch(void* const* d_in, const int* in_sizes, int n_in,
                              void* d_out, int out_size, void* d_ws, size_t ws_size,
                              hipStream_t stream) {
  const float* x   = (const float*)d_in[0];
  const int* edge  = (const int*)d_in[1];
  const int E = in_sizes[1] / 2;
  const int* esrc = edge;
  const int* edst = edge + E;
  const float* W0l = (const float*)d_in[2];
  const float* W0r = (const float*)d_in[3];
  const float* b0  = (const float*)d_in[4];
  const float* g0  = (const float*)d_in[5];
  const float* be0 = (const float*)d_in[6];
  const float* W1l = (const float*)d_in[7];
  const float* W1r = (const float*)d_in[8];
  const float* b1  = (const float*)d_in[9];
  const float* g1  = (const float*)d_in[10];
  const float* be1 = (const float*)d_in[11];
  const float* W2l = (const float*)d_in[12];
  const float* W2r = (const float*)d_in[13];
  const float* b2  = (const float*)d_in[14];
  float* out = (float*)d_out;

  const int n = NN;
  // ---- workspace layout ----
  int* off   = (int*)d_ws;               // 50304
  int* cur   = off + 50304;              // 50304
  int* btot  = cur + 50304;              // 256
  int* boff  = btot + 256;               // 256
  float* stats = (float*)(boff + 256);   // 512 (stats0 | stats1)
  u16* ssrc  = (u16*)(stats + 512);      // 800064 u16
  u16* Wt    = ssrc + 800064;            // 6*16384
  u16* ylb   = Wt + 6 * 16384;           // n*128 bf16
  float* ha  = (float*)(ylb + (size_t)n * 128);  // n*128 fp32
  float* hb  = ha + (size_t)n * 128;             // n*128 fp32
  float* stats0 = stats;
  float* stats1 = stats + 256;

  const int TB = 256;
  const int NB1 = (n + 255) / 256;

  // ---- CSR build ----
  zero_misc_kernel<<<NB1, TB, 0, stream>>>(cur, stats, n);
  hist_kernel<<<(E + TB - 1) / TB, TB, 0, stream>>>(edst, cur, E);
  scan1_kernel<<<NB1, TB, 0, stream>>>(cur, off, btot, n);
  scan2_kernel<<<1, TB, 0, stream>>>(btot, boff, off + n, NB1);
  scan3_kernel<<<NB1, TB, 0, stream>>>(off, cur, boff, n);
  fill_kernel<<<(E + TB - 1) / TB, TB, 0, stream>>>(esrc, edst, cur, ssrc, E);

  convert_w_kernel<<<6, TB, 0, stream>>>(W0l, W0r, W1l, W1r, W2l, W2r, Wt);

  const int GB = (n + 127) / 128;

  // ---- layer 0: gemm(x) -> ylb, ha; agg; stats0 ----
  gemm_dual_kernel<128, 128, LOAD_CVT><<<GB, TB, 0, stream>>>(
      x, Wt + 0 * 16384, Wt + 1 * 16384, b0, nullptr, nullptr, nullptr, ylb, ha, n);
  aggregate_kernel<128><<<(n + 7) / 8, TB, 0, stream>>>(ylb, off, ssrc, ha, n);
  bnstats_kernel<<<256, TB, 0, stream>>>(ha, stats0, n);

  // ---- layer 1: gemm(BN0+GELU(ha)) -> ylb, hb; agg; stats1 ----
  gemm_dual_kernel<128, 128, LOAD_BN><<<GB, TB, 0, stream>>>(
      ha, Wt + 2 * 16384, Wt + 3 * 16384, b1, stats0, g0, be0, ylb, hb, n);
  aggregate_kernel<128><<<(n + 7) / 8, TB, 0, stream>>>(ylb, off, ssrc, hb, n);
  bnstats_kernel<<<256, TB, 0, stream>>>(hb, stats1, n);

  // ---- layer 2: gemm(BN1+GELU(hb)) -> ylb, out; agg ----
  gemm_dual_kernel<64, 64, LOAD_BN><<<GB, TB, 0, stream>>>(
      hb, Wt + 4 * 16384, Wt + 5 * 16384, b2, stats1, g1, be1, ylb, out, n);
  aggregate_kernel<64><<<(n + 15) / 16, TB, 0, stream>>>(ylb, off, ssrc, out, n);
}